// Round 1
// 589.180 us; speedup vs baseline: 1.2749x; 1.2749x over previous
//
#include <hip/hip_runtime.h>

#define NN 100000
#define NE 1600000
#define NE2 1700000
#define OUT_EI 3200000
#define OUT_AL 6600000
#define SLOPE 0.2f
#define NB 391       // ceil(NN/256): scan blocks AND dst buckets (256 nodes each)
#define EPB 6400     // edges per block in binning kernels
#define NBB 250      // NE / EPB

typedef unsigned short u16;
typedef unsigned int u32;
typedef __bf16 bf16x8 __attribute__((ext_vector_type(8)));
typedef float f32x4 __attribute__((ext_vector_type(4)));
typedef u32 u32x4 __attribute__((ext_vector_type(4)));

__device__ __forceinline__ float bf2f(u16 u){ return __uint_as_float(((u32)u) << 16); }
__device__ __forceinline__ u16 f2bf(float f){
    u32 x = __float_as_uint(f);
    x += 0x7FFFu + ((x >> 16) & 1u);   // round-to-nearest-even
    return (u16)(x >> 16);
}
__device__ __forceinline__ float eluf(float v){ return v > 0.f ? v : (__expf(v) - 1.f); }
__device__ __forceinline__ float lreluf(float v){ return fmaxf(v, SLOPE * v); }

// ================= bucketed CSR build =================
// bucket hist: LDS-aggregated counts of dst>>8
__global__ __launch_bounds__(256) void k_bhist(const int* __restrict__ ei, int* __restrict__ bcnt){
    __shared__ int s[NB];
    int t = threadIdx.x;
    for (int i = t; i < NB; i += 256) s[i] = 0;
    __syncthreads();
    int e0 = blockIdx.x * EPB;
    for (int i = t; i < EPB; i += 256)
        atomicAdd(&s[ei[NE + e0 + i] >> 8], 1);
    __syncthreads();
    for (int i = t; i < NB; i += 256) if (s[i]) atomicAdd(&bcnt[i], s[i]);
}

__global__ void k_bscan(const int* __restrict__ bcnt, int* __restrict__ bbase, int* __restrict__ bcur){
    __shared__ int s[512];
    int t = threadIdx.x;                              // 512 threads
    int v = (t < NB) ? bcnt[t] : 0;
    s[t] = v; __syncthreads();
    #pragma unroll
    for (int d = 1; d < 512; d <<= 1){
        int x = (t >= d) ? s[t - d] : 0;
        __syncthreads();
        s[t] += x;
        __syncthreads();
    }
    if (t < NB){ int ex = s[t] - v; bbase[t] = ex; bcur[t] = ex; }
    if (t == 0) bbase[NB] = NE;
}

// bucket scatter: block-aggregated chunk reservation -> dense write runs per bucket.
// payload (src, ale1, ale2) read SEQUENTIALLY in original edge order, carried in bins.
__global__ __launch_bounds__(256) void k_bscatter(const int* __restrict__ ei, const u16* __restrict__ ale1,
                                                  const u16* __restrict__ ale2,
                                                  int* __restrict__ bcur, int4* __restrict__ bins,
                                                  u16* __restrict__ binsA2){
    __shared__ int cnt[NB];
    __shared__ int base[NB];
    int t = threadIdx.x;
    for (int i = t; i < NB; i += 256) cnt[i] = 0;
    __syncthreads();
    int e0 = blockIdx.x * EPB;
    for (int i = t; i < EPB; i += 256)
        atomicAdd(&cnt[ei[NE + e0 + i] >> 8], 1);
    __syncthreads();
    for (int i = t; i < NB; i += 256){
        int c = cnt[i];
        base[i] = c ? atomicAdd(&bcur[i], c) : 0;
        cnt[i] = 0;
    }
    __syncthreads();
    const u32* a1 = (const u32*)ale1;                 // 2 u32 per edge
    for (int i = t; i < EPB; i += 256){
        int e = e0 + i;
        int dst = ei[NE + e];
        int b = dst >> 8;
        int r = atomicAdd(&cnt[b], 1);
        int pos = base[b] + r;
        int4 v;
        v.x = ei[e];                                  // src
        v.y = dst;
        v.z = (int)a1[2 * e];
        v.w = (int)a1[2 * e + 1];
        bins[pos] = v;
        binsA2[pos] = ale2[e];
    }
}

// per-bucket degree hist in LDS (replaces global-atomic k_hist)
__global__ __launch_bounds__(256) void k_bdeg(const int4* __restrict__ bins, const int* __restrict__ bbase,
                                              int* __restrict__ deg){
    __shared__ int d[256];
    int t = threadIdx.x, b = blockIdx.x;
    d[t] = 0;
    __syncthreads();
    int s = bbase[b], e2 = bbase[b + 1];
    const int* bd = (const int*)bins;
    for (int i = s + t; i < e2; i += 256)
        atomicAdd(&d[bd[(size_t)i * 4 + 1] & 255], 1);
    __syncthreads();
    int n = b * 256 + t;
    if (n < NN) deg[n] = d[t];
}

__global__ __launch_bounds__(256) void k_scan_blk(const int* __restrict__ deg, int* __restrict__ part,
                                                  int* __restrict__ bsum){
    __shared__ int s[256];
    int t = threadIdx.x;
    int i = blockIdx.x * 256 + t;
    int v = (i < NN) ? deg[i] : 0;
    s[t] = v; __syncthreads();
    #pragma unroll
    for (int d = 1; d < 256; d <<= 1){
        int x = (t >= d) ? s[t - d] : 0;
        __syncthreads();
        s[t] += x;
        __syncthreads();
    }
    if (i < NN) part[i] = s[t] - v;                  // exclusive within block
    if (t == 255) bsum[blockIdx.x] = s[255];
}

__global__ void k_scan_top(int* __restrict__ bsum){
    __shared__ int s[512];
    int t = threadIdx.x;                             // 512 threads
    int v = (t < NB) ? bsum[t] : 0;
    s[t] = v; __syncthreads();
    #pragma unroll
    for (int d = 1; d < 512; d <<= 1){
        int x = (t >= d) ? s[t - d] : 0;
        __syncthreads();
        s[t] += x;
        __syncthreads();
    }
    bsum[t] = s[t] - v;                              // exclusive
}

__global__ __launch_bounds__(256) void k_scan_add(const int* __restrict__ part, const int* __restrict__ bsum,
                                                  int* __restrict__ offsets){
    int i = blockIdx.x * 256 + threadIdx.x;
    if (i >= NN) return;
    offsets[i] = part[i] + bsum[i >> 8] + i;         // +i: one self-loop slot per preceding node
    if (i == 0) offsets[NN] = NE + NN;
}

// fine scatter: one block per bucket, LDS cursors; writes stay L2-local & dense.
__global__ __launch_bounds__(256) void k_fscatter(const int4* __restrict__ bins, const u16* __restrict__ binsA2,
                                                  const int* __restrict__ bbase, const int* __restrict__ offsets,
                                                  int* __restrict__ src32, ushort4* __restrict__ ale1p,
                                                  u16* __restrict__ ale2p){
    __shared__ int cur[256];
    int t = threadIdx.x, b = blockIdx.x;
    int n = b * 256 + t;
    if (n < NN) cur[t] = offsets[n] + 1;             // real edges start after self-loop slot
    __syncthreads();
    int s = bbase[b], e2 = bbase[b + 1];
    for (int i = s + t; i < e2; i += 256){
        int4 v = bins[i];
        int pos = atomicAdd(&cur[v.y & 255], 1);
        src32[pos] = v.x;
        uint2 a; a.x = (u32)v.z; a.y = (u32)v.w;
        ((uint2*)ale1p)[pos] = a;
        ale2p[pos] = binsA2[i];
    }
}

// ================= small precomputes =================
__global__ void k_q(const float* __restrict__ W1e, const float* __restrict__ a1e,
                    const float* __restrict__ W2e, const float* __restrict__ a2e,
                    float* __restrict__ q1, float* __restrict__ q2){
    int t = threadIdx.x;           // 64 threads
    int k = t >> 2, h = t & 3;
    float s = 0.f;
    for (int c = 0; c < 32; c++) s += W1e[k * 128 + h * 32 + c] * a1e[h * 32 + c];
    q1[t] = s;
    if (t < 16){
        float s2 = 0.f;
        for (int c = 0; c < 32; c++) s2 += W2e[t * 32 + c] * a2e[c];
        q2[t] = s2;
    }
}

__global__ __launch_bounds__(256) void k_ale(const float* __restrict__ eattr,
                                             const float* __restrict__ q1, const float* __restrict__ q2,
                                             u16* __restrict__ ale1, u16* __restrict__ ale2){
    __shared__ float sq1[64], sq2[16];
    int t = threadIdx.x;
    if (t < 64) sq1[t] = q1[t];
    if (t < 16) sq2[t] = q2[t];
    __syncthreads();
    int gt = blockIdx.x * 256 + t;                   // NE*4 exact
    int e = gt >> 2, part = gt & 3;
    f32x4 av = ((const f32x4*)eattr)[(size_t)e * 4 + part];
    int j0 = part * 4;
    float p0 = 0, p1 = 0, p2 = 0, p3 = 0, p4 = 0;
    #pragma unroll
    for (int k = 0; k < 4; k++){
        float a = av[k]; int j = j0 + k;
        p0 += a * sq1[j * 4 + 0]; p1 += a * sq1[j * 4 + 1];
        p2 += a * sq1[j * 4 + 2]; p3 += a * sq1[j * 4 + 3];
        p4 += a * sq2[j];
    }
    #pragma unroll
    for (int m = 1; m < 4; m <<= 1){
        p0 += __shfl_xor(p0, m); p1 += __shfl_xor(p1, m);
        p2 += __shfl_xor(p2, m); p3 += __shfl_xor(p3, m); p4 += __shfl_xor(p4, m);
    }
    if (part == 0){
        ushort4 w; w.x = f2bf(p0); w.y = f2bf(p1); w.z = f2bf(p2); w.w = f2bf(p3);
        ((ushort4*)ale1)[e] = w;
        ale2[e] = f2bf(p4);
    }
}

// ================= GEMMs =================
__global__ __launch_bounds__(256) void k_gemm1(const float* __restrict__ x, const float* __restrict__ W,
                                               u16* __restrict__ h1){
    __shared__ __align__(16) u16 sW[128 * 136];      // transposed: sW[col*136+k]
    int t = threadIdx.x;
    for (int i = t; i < 128 * 128; i += 256){
        int k = i >> 7, c = i & 127;
        sW[c * 136 + k] = f2bf(W[i]);
    }
    __syncthreads();
    int lane = t & 63, wave = t >> 6;
    int quad = lane >> 4, m16 = lane & 15;
    int rowA = blockIdx.x * 64 + wave * 16 + m16;
    bf16x8 afr[4];
    if (rowA < NN){
        const f32x4* xr = (const f32x4*)(x + (size_t)rowA * 128);
        #pragma unroll
        for (int kk = 0; kk < 4; kk++){
            f32x4 va = xr[kk * 8 + quad * 2];
            f32x4 vb = xr[kk * 8 + quad * 2 + 1];
            #pragma unroll
            for (int i = 0; i < 4; i++){ afr[kk][i] = (__bf16)va[i]; afr[kk][4 + i] = (__bf16)vb[i]; }
        }
    } else {
        #pragma unroll
        for (int kk = 0; kk < 4; kk++)
            #pragma unroll
            for (int i = 0; i < 8; i++) afr[kk][i] = (__bf16)0.f;
    }
    int rowbase = blockIdx.x * 64 + wave * 16 + quad * 4;
    #pragma unroll
    for (int nt = 0; nt < 8; nt++){
        f32x4 acc = (f32x4){0.f, 0.f, 0.f, 0.f};
        const u16* wp = &sW[(nt * 16 + m16) * 136 + quad * 8];
        #pragma unroll
        for (int kk = 0; kk < 4; kk++){
            bf16x8 bfr = *(const bf16x8*)(wp + kk * 32);
            acc = __builtin_amdgcn_mfma_f32_16x16x32_bf16(afr[kk], bfr, acc, 0, 0, 0);
        }
        int col = nt * 16 + m16;
        #pragma unroll
        for (int r = 0; r < 4; r++){
            int row = rowbase + r;
            if (row < NN) h1[(size_t)row * 128 + col] = f2bf(acc[r]);
        }
    }
}

__global__ __launch_bounds__(256) void k_gemm2(const u16* __restrict__ hin, const float* __restrict__ W,
                                               float* __restrict__ h2a){
    __shared__ __align__(16) u16 sW[32 * 136];
    int t = threadIdx.x;
    for (int i = t; i < 128 * 32; i += 256){
        int k = i >> 5, c = i & 31;
        sW[c * 136 + k] = f2bf(W[i]);
    }
    __syncthreads();
    int lane = t & 63, wave = t >> 6;
    int quad = lane >> 4, m16 = lane & 15;
    int rowA = blockIdx.x * 64 + wave * 16 + m16;
    bf16x8 afr[4];
    if (rowA < NN){
        const u16* xr = hin + (size_t)rowA * 128 + quad * 8;
        #pragma unroll
        for (int kk = 0; kk < 4; kk++) afr[kk] = *(const bf16x8*)(xr + kk * 32);
    } else {
        #pragma unroll
        for (int kk = 0; kk < 4; kk++)
            #pragma unroll
            for (int i = 0; i < 8; i++) afr[kk][i] = (__bf16)0.f;
    }
    int rowbase = blockIdx.x * 64 + wave * 16 + quad * 4;
    #pragma unroll
    for (int nt = 0; nt < 2; nt++){
        f32x4 acc = (f32x4){0.f, 0.f, 0.f, 0.f};
        const u16* wp = &sW[(nt * 16 + m16) * 136 + quad * 8];
        #pragma unroll
        for (int kk = 0; kk < 4; kk++){
            bf16x8 bfr = *(const bf16x8*)(wp + kk * 32);
            acc = __builtin_amdgcn_mfma_f32_16x16x32_bf16(afr[kk], bfr, acc, 0, 0, 0);
        }
        int col = nt * 16 + m16;
        #pragma unroll
        for (int r = 0; r < 4; r++){
            int row = rowbase + r;
            if (row < NN) h2a[(size_t)row * 32 + col] = acc[r];
        }
    }
}

// ================= per-node logits =================
__global__ __launch_bounds__(256) void k_al1(const u16* __restrict__ h1, const float* __restrict__ a1s,
                                             const float* __restrict__ a1d,
                                             float* __restrict__ al_s, float* __restrict__ al_d){
    int idx = blockIdx.x * 256 + threadIdx.x;   // NN*128 exact
    int j = idx & 127;
    float v = bf2f(h1[idx]);
    float vs = v * a1s[j];
    float vd = v * a1d[j];
    #pragma unroll
    for (int m = 1; m < 32; m <<= 1){ vs += __shfl_xor(vs, m); vd += __shfl_xor(vd, m); }
    if ((threadIdx.x & 31) == 0){
        int n = idx >> 7, h = j >> 5;
        al_s[n * 4 + h] = vs;
        al_d[n * 4 + h] = vd;
    }
}

__global__ __launch_bounds__(256) void k_al2(const float* __restrict__ h2a, const float* __restrict__ a2s,
                                             const float* __restrict__ a2d,
                                             float* __restrict__ al_s, float* __restrict__ al_d){
    int idx = blockIdx.x * 256 + threadIdx.x;   // NN*32 exact
    int c = idx & 31;
    float v = h2a[idx];
    float vs = v * a2s[c];
    float vd = v * a2d[c];
    #pragma unroll
    for (int m = 1; m < 32; m <<= 1){ vs += __shfl_xor(vs, m); vd += __shfl_xor(vd, m); }
    if ((threadIdx.x & 31) == 0){
        int n = idx >> 5;
        al_s[n] = vs;
        al_d[n] = vd;
    }
}

// ================= layer 1: per-node softmax + aggregate (wave per node) =================
__global__ __launch_bounds__(256) void k_node1(const int* __restrict__ src32, const ushort4* __restrict__ ale1p,
                                               const int* __restrict__ offsets,
                                               const float* __restrict__ al_s, const float* __restrict__ al_d,
                                               const u16* __restrict__ h1, const float* __restrict__ b1,
                                               u16* __restrict__ h1b, ushort4* __restrict__ pb1){
    int wave = threadIdx.x >> 6, lane = threadIdx.x & 63;
    int n = blockIdx.x * 4 + wave;               // 25000*4 = NN exact
    int start = offsets[n], end = offsets[n + 1];
    int degr = end - start - 1;
    f32x4 ald  = ((const f32x4*)al_d)[n];
    f32x4 alsn = ((const f32x4*)al_s)[n];
    float z0 = 0, z1 = 0, z2 = 0, z3 = 0, s0 = 0, s1 = 0, s2 = 0, s3 = 0;
    for (int i = start + 1 + lane; i < end; i += 64){
        int src = src32[i];
        ushort4 av = ale1p[i];
        f32x4 als = ((const f32x4*)al_s)[src];
        float a0 = bf2f(av.x), a1 = bf2f(av.y), a2 = bf2f(av.z), a3 = bf2f(av.w);
        float e0 = __expf(lreluf(als[0] + ald[0] + a0));
        float e1 = __expf(lreluf(als[1] + ald[1] + a1));
        float e2 = __expf(lreluf(als[2] + ald[2] + a2));
        float e3 = __expf(lreluf(als[3] + ald[3] + a3));
        z0 += e0; z1 += e1; z2 += e2; z3 += e3;
        s0 += a0; s1 += a1; s2 += a2; s3 += a3;
        ushort4 w; w.x = f2bf(e0); w.y = f2bf(e1); w.z = f2bf(e2); w.w = f2bf(e3);
        pb1[i] = w;
    }
    #pragma unroll
    for (int m = 1; m < 64; m <<= 1){
        z0 += __shfl_xor(z0, m); z1 += __shfl_xor(z1, m); z2 += __shfl_xor(z2, m); z3 += __shfl_xor(z3, m);
        s0 += __shfl_xor(s0, m); s1 += __shfl_xor(s1, m); s2 += __shfl_xor(s2, m); s3 += __shfl_xor(s3, m);
    }
    float inv_deg = 1.f / fmaxf((float)degr, 1.f);
    float p0 = __expf(lreluf(alsn[0] + ald[0] + s0 * inv_deg)); z0 += p0;
    float p1 = __expf(lreluf(alsn[1] + ald[1] + s1 * inv_deg)); z1 += p1;
    float p2 = __expf(lreluf(alsn[2] + ald[2] + s2 * inv_deg)); z2 += p2;
    float p3 = __expf(lreluf(alsn[3] + ald[3] + s3 * inv_deg)); z3 += p3;
    int g = lane >> 4, l = lane & 15, hq = l >> 2;   // channels 8l..8l+7, head = l>>2
    float rz = 1.f / ((hq == 0) ? z0 : (hq == 1) ? z1 : (hq == 2) ? z2 : z3);
    float ps = (hq == 0) ? p0 : (hq == 1) ? p1 : (hq == 2) ? p2 : p3;
    const u32x4* h1v = (const u32x4*)h1;             // 16 u32x4 per row
    const u16* pbu = (const u16*)pb1;
    float acc[8];
    #pragma unroll
    for (int k = 0; k < 8; k++) acc[k] = 0.f;
    for (int i = start + g; i < end; i += 4){
        bool slf = (i == start);                     // group-uniform
        int src = slf ? n : src32[i];
        float p = slf ? ps : bf2f(pbu[(size_t)i * 4 + hq]);
        u32x4 v = h1v[(size_t)src * 16 + l];
        #pragma unroll
        for (int k = 0; k < 4; k++){
            acc[2 * k]     += p * bf2f((u16)(v[k] & 0xFFFFu));
            acc[2 * k + 1] += p * bf2f((u16)(v[k] >> 16));
        }
    }
    #pragma unroll
    for (int k = 0; k < 8; k++){
        acc[k] += __shfl_xor(acc[k], 16);
        acc[k] += __shfl_xor(acc[k], 32);
    }
    if (g == 0){
        u32x4 w;
        #pragma unroll
        for (int k = 0; k < 4; k++){
            float v0 = eluf(acc[2 * k]     * rz + b1[l * 8 + 2 * k]);
            float v1 = eluf(acc[2 * k + 1] * rz + b1[l * 8 + 2 * k + 1]);
            w[k] = (u32)f2bf(v0) | ((u32)f2bf(v1) << 16);
        }
        ((u32x4*)h1b)[(size_t)n * 16 + l] = w;
    }
}

// ================= layer 2: per-node softmax + aggregate =================
// alpha for real edges now produced by k_alpha in original edge order (sequential writes)
__global__ __launch_bounds__(256) void k_node2(const int* __restrict__ src32, const u16* __restrict__ ale2p,
                                               const int* __restrict__ offsets,
                                               const float* __restrict__ al_s, const float* __restrict__ al_d,
                                               const float* __restrict__ h2a, const float* __restrict__ b2,
                                               float* __restrict__ dout, u16* __restrict__ pb2,
                                               float* __restrict__ rzv){
    int wave = threadIdx.x >> 6, lane = threadIdx.x & 63;
    int n = blockIdx.x * 4 + wave;
    int start = offsets[n], end = offsets[n + 1];
    int degr = end - start - 1;
    float aldn = al_d[n];
    float z = 0.f, sa = 0.f;
    for (int i = start + 1 + lane; i < end; i += 64){
        int src = src32[i];
        float a = bf2f(ale2p[i]);
        float ev = __expf(lreluf(al_s[src] + aldn + a));
        z += ev; sa += a;
        pb2[i] = f2bf(ev);
    }
    #pragma unroll
    for (int m = 1; m < 64; m <<= 1){ z += __shfl_xor(z, m); sa += __shfl_xor(sa, m); }
    float mal = sa / fmaxf((float)degr, 1.f);
    float pself = __expf(lreluf(al_s[n] + aldn + mal));
    z += pself;
    float rz = 1.f / z;
    if (lane == 0){
        rzv[n] = rz;
        dout[OUT_AL + NE + n] = pself * rz;          // self-loop alpha
    }
    int g = lane >> 3, l = lane & 7;                 // channels l*4..l*4+3
    const f32x4* h2v = (const f32x4*)h2a;            // 8 f32x4 per row
    f32x4 acc = (f32x4){0.f, 0.f, 0.f, 0.f};
    for (int i = start + g; i < end; i += 8){
        bool slf = (i == start);                     // group-uniform
        int src = slf ? n : src32[i];
        float alpha = (slf ? pself : bf2f(pb2[i])) * rz;
        f32x4 v = h2v[(size_t)src * 8 + l];
        #pragma unroll
        for (int k = 0; k < 4; k++) acc[k] += alpha * v[k];
    }
    #pragma unroll
    for (int k = 0; k < 4; k++){
        acc[k] += __shfl_xor(acc[k], 8);
        acc[k] += __shfl_xor(acc[k], 16);
        acc[k] += __shfl_xor(acc[k], 32);
    }
    if (g == 0){
        f32x4 w;
        #pragma unroll
        for (int k = 0; k < 4; k++) w[k] = eluf(acc[k] + b2[l * 4 + k]);
        ((f32x4*)dout)[(size_t)n * 8 + l] = w;
    }
}

// alpha for real edges, original edge order: sequential writes, fp32 numerator
__global__ __launch_bounds__(256) void k_alpha(const int* __restrict__ ei, const u16* __restrict__ ale2,
                                               const float* __restrict__ al_s, const float* __restrict__ al_d,
                                               const float* __restrict__ rzv, float* __restrict__ dout){
    int e = blockIdx.x * 256 + threadIdx.x;          // NE exact
    int src = ei[e], dst = ei[NE + e];
    float a = bf2f(ale2[e]);
    float ev = __expf(lreluf(al_s[src] + al_d[dst] + a));
    dout[OUT_AL + e] = ev * rzv[dst];
}

// ================= edge_index_sl output (f32 values) =================
__global__ __launch_bounds__(256) void k_eidx(const int* __restrict__ ei, float* __restrict__ dout){
    int i = blockIdx.x * 256 + threadIdx.x;
    if (i >= 2 * NE2) return;
    int val;
    if (i < NE2) val = (i < NE) ? ei[i] : (i - NE);
    else { int e = i - NE2; val = (e < NE) ? ei[NE + e] : (e - NE); }
    dout[OUT_EI + i] = (float)val;
}

extern "C" void kernel_launch(void* const* d_in, const int* in_sizes, int n_in,
                              void* d_out, int out_size, void* d_ws, size_t ws_size,
                              hipStream_t stream) {
    const float* x     = (const float*)d_in[0];
    const int*   ei    = (const int*)d_in[1];
    const float* eattr = (const float*)d_in[2];
    const float* W1    = (const float*)d_in[3];
    const float* W1e   = (const float*)d_in[4];
    const float* a1s   = (const float*)d_in[5];
    const float* a1d   = (const float*)d_in[6];
    const float* a1e   = (const float*)d_in[7];
    const float* b1    = (const float*)d_in[8];
    const float* W2    = (const float*)d_in[9];
    const float* W2e   = (const float*)d_in[10];
    const float* a2s   = (const float*)d_in[11];
    const float* a2d   = (const float*)d_in[12];
    const float* a2e   = (const float*)d_in[13];
    const float* b2    = (const float*)d_in[14];
    float* dout = (float*)d_out;

    char* ws = (char*)d_ws;
    size_t off = 0;
    auto alloc = [&](size_t bytes) -> void* {
        void* p = ws + off;
        off += (bytes + 255) & ~(size_t)255;
        return p;
    };
    // --- zero-initialized: bucket counters only ---
    int* bcnt = (int*)alloc((size_t)NB * 4);
    size_t zero_bytes = off;
    // --- rest fully written before read ---
    int*     deg     = (int*)alloc((size_t)NN * 4);          // written by k_bdeg (no memset)
    int*     part    = (int*)alloc((size_t)NN * 4);
    int*     bsum    = (int*)alloc(512 * 4);
    int*     offsets = (int*)alloc((size_t)(NN + 1) * 4);
    int*     bbase   = (int*)alloc((size_t)(NB + 1) * 4);
    int*     bcur    = (int*)alloc((size_t)NB * 4);
    int4*    bins    = (int4*)alloc((size_t)NE * 16);        // dead after k_fscatter
    u16*     binsA2  = (u16*)alloc((size_t)NE * 2);
    int*     src32   = (int*)alloc((size_t)NE2 * 4);
    ushort4* ale1p   = (ushort4*)alloc((size_t)NE2 * 8);
    u16*     ale2p   = (u16*)alloc((size_t)NE2 * 2);
    float*   q1      = (float*)alloc(64 * 4);
    float*   q2      = (float*)alloc(16 * 4);
    u16*     ale1    = (u16*)alloc((size_t)NE * 4 * 2);      // dead after k_bscatter
    u16*     ale2    = (u16*)alloc((size_t)NE * 2);          // live until k_alpha
    float*   al_s1   = (float*)alloc((size_t)NN * 4 * 4);
    float*   al_d1   = (float*)alloc((size_t)NN * 4 * 4);
    u16*     h1      = (u16*)alloc((size_t)NN * 128 * 2);    // dead after k_node1
    u16*     h1b     = (u16*)alloc((size_t)NN * 128 * 2);
    // aliases into dead regions
    ushort4* pb1   = (ushort4*)bins;                         // NE2*8 = 13.6 MB <= 25.6 MB
    u16*   pb2   = (u16*)ale1;                               // NE2*2 = 3.4 MB <= 12.8 MB
    char*  h1r   = (char*)h1;
    float* h2a   = (float*)(h1r);                            // NN*32*4 = 12.8 MB
    float* al_s2 = (float*)(h1r + 12800000);                 // NN*4
    float* al_d2 = (float*)(h1r + 13200128);                 // NN*4
    float* rzv   = (float*)(h1r + 13600256);                 // NN*4

    const int TB = 256;
    hipMemsetAsync(d_ws, 0, zero_bytes, stream);

    // precomputes
    k_q<<<1, 64, 0, stream>>>(W1e, a1e, W2e, a2e, q1, q2);
    k_ale<<<NE * 4 / TB, TB, 0, stream>>>(eattr, q1, q2, ale1, ale2);
    // bucketed CSR build
    k_bhist<<<NBB, TB, 0, stream>>>(ei, bcnt);
    k_bscan<<<1, 512, 0, stream>>>(bcnt, bbase, bcur);
    k_bscatter<<<NBB, TB, 0, stream>>>(ei, ale1, ale2, bcur, bins, binsA2);
    k_bdeg<<<NB, TB, 0, stream>>>(bins, bbase, deg);
    k_scan_blk<<<NB, TB, 0, stream>>>(deg, part, bsum);
    k_scan_top<<<1, 512, 0, stream>>>(bsum);
    k_scan_add<<<NB, TB, 0, stream>>>(part, bsum, offsets);
    k_fscatter<<<NB, TB, 0, stream>>>(bins, binsA2, bbase, offsets, src32, ale1p, ale2p);
    // layer 1
    k_gemm1<<<(NN + 63) / 64, TB, 0, stream>>>(x, W1, h1);
    k_al1<<<NN * 128 / TB, TB, 0, stream>>>(h1, a1s, a1d, al_s1, al_d1);
    k_node1<<<NN / 4, TB, 0, stream>>>(src32, ale1p, offsets, al_s1, al_d1, h1, b1, h1b, pb1);
    // layer 2 (h1 region reused as h2a/al2/rzv; ale1 region reused as pb2)
    k_gemm2<<<(NN + 63) / 64, TB, 0, stream>>>(h1b, W2, h2a);
    k_al2<<<NN * 32 / TB, TB, 0, stream>>>(h2a, a2s, a2d, al_s2, al_d2);
    k_node2<<<NN / 4, TB, 0, stream>>>(src32, ale2p, offsets, al_s2, al_d2, h2a, b2, dout, pb2, rzv);
    k_alpha<<<NE / TB, TB, 0, stream>>>(ei, ale2, al_s2, al_d2, rzv, dout);
    // edge index output
    k_eidx<<<(2 * NE2 + TB - 1) / TB, TB, 0, stream>>>(ei, dout);
}

// Round 2
// 562.129 us; speedup vs baseline: 1.3362x; 1.0481x over previous
//
#include <hip/hip_runtime.h>

#define NN 100000
#define NE 1600000
#define NE2 1700000
#define OUT_EI 3200000
#define OUT_AL 6600000
#define SLOPE 0.2f
#define NB 391       // ceil(NN/256): dst buckets (256 nodes each)
#define EPB 6400     // edges per block in binning kernels
#define NBB 250      // NE / EPB

typedef unsigned short u16;
typedef unsigned int u32;
typedef __bf16 bf16x8 __attribute__((ext_vector_type(8)));
typedef float f32x4 __attribute__((ext_vector_type(4)));
typedef u32 u32x4 __attribute__((ext_vector_type(4)));

__device__ __forceinline__ float bf2f(u16 u){ return __uint_as_float(((u32)u) << 16); }
__device__ __forceinline__ u16 f2bf(float f){
    u32 x = __float_as_uint(f);
    x += 0x7FFFu + ((x >> 16) & 1u);   // round-to-nearest-even
    return (u16)(x >> 16);
}
__device__ __forceinline__ float eluf(float v){ return v > 0.f ? v : (__expf(v) - 1.f); }
__device__ __forceinline__ float lreluf(float v){ return fmaxf(v, SLOPE * v); }
__device__ __forceinline__ float sel4f(float a, float b, float c, float d, int s){
    float x = (s & 1) ? b : a;
    float y = (s & 1) ? d : c;
    return (s & 2) ? y : x;
}

// ================= bucketed CSR build =================
__global__ __launch_bounds__(256) void k_bhist(const int* __restrict__ ei, int* __restrict__ bcnt){
    __shared__ int s[NB];
    int t = threadIdx.x;
    for (int i = t; i < NB; i += 256) s[i] = 0;
    __syncthreads();
    int e0 = blockIdx.x * EPB;
    for (int i = t; i < EPB; i += 256)
        atomicAdd(&s[ei[NE + e0 + i] >> 8], 1);
    __syncthreads();
    for (int i = t; i < NB; i += 256) if (s[i]) atomicAdd(&bcnt[i], s[i]);
}

__global__ void k_bscan(const int* __restrict__ bcnt, int* __restrict__ bbase, int* __restrict__ bcur){
    __shared__ int s[512];
    int t = threadIdx.x;                              // 512 threads
    int v = (t < NB) ? bcnt[t] : 0;
    s[t] = v; __syncthreads();
    #pragma unroll
    for (int d = 1; d < 512; d <<= 1){
        int x = (t >= d) ? s[t - d] : 0;
        __syncthreads();
        s[t] += x;
        __syncthreads();
    }
    if (t < NB){ int ex = s[t] - v; bbase[t] = ex; bcur[t] = ex; }
    if (t == 0) bbase[NB] = NE;
}

// bucket scatter: block-aggregated chunk reservation -> dense write runs per bucket.
// payload read SEQUENTIALLY; packed bin = (dstLow8 << 24) | src24.
__global__ __launch_bounds__(256) void k_bscatter(const int* __restrict__ ei, const u16* __restrict__ ale1,
                                                  const u16* __restrict__ ale2,
                                                  int* __restrict__ bcur, u32* __restrict__ binsP,
                                                  uint2* __restrict__ binsA, u16* __restrict__ binsA2){
    __shared__ int cnt[NB];
    __shared__ int base[NB];
    __shared__ int sdst[EPB];
    int t = threadIdx.x;
    for (int i = t; i < NB; i += 256) cnt[i] = 0;
    __syncthreads();
    int e0 = blockIdx.x * EPB;
    for (int i = t; i < EPB; i += 256){
        int dv = ei[NE + e0 + i];
        sdst[i] = dv;
        atomicAdd(&cnt[dv >> 8], 1);
    }
    __syncthreads();
    for (int i = t; i < NB; i += 256){
        int c = cnt[i];
        base[i] = c ? atomicAdd(&bcur[i], c) : 0;
        cnt[i] = 0;
    }
    __syncthreads();
    const uint2* a1 = (const uint2*)ale1;
    for (int i = t; i < EPB; i += 256){
        int e = e0 + i;
        int dst = sdst[i];
        int b = dst >> 8;
        int r = atomicAdd(&cnt[b], 1);
        int pos = base[b] + r;
        binsP[pos] = ((u32)(dst & 255) << 24) | (u32)ei[e];
        binsA[pos] = a1[e];
        binsA2[pos] = ale2[e];
    }
}

// merged: per-bucket degree hist + 256-wide scan -> offsets + fine scatter (LDS cursors)
__global__ __launch_bounds__(256) void k_fscatter(const u32* __restrict__ binsP, const uint2* __restrict__ binsA,
                                                  const u16* __restrict__ binsA2, const int* __restrict__ bbase,
                                                  int* __restrict__ offsets,
                                                  int* __restrict__ src32, uint2* __restrict__ ale1p,
                                                  u16* __restrict__ ale2p){
    __shared__ int d[256];
    __shared__ int s[256];
    __shared__ int cur[256];
    int t = threadIdx.x, b = blockIdx.x;
    d[t] = 0;
    __syncthreads();
    int bs = bbase[b], be = bbase[b + 1];
    for (int i = bs + t; i < be; i += 256)
        atomicAdd(&d[binsP[i] >> 24], 1);
    __syncthreads();
    int v = d[t];
    s[t] = v; __syncthreads();
    #pragma unroll
    for (int dd = 1; dd < 256; dd <<= 1){
        int x = (t >= dd) ? s[t - dd] : 0;
        __syncthreads();
        s[t] += x;
        __syncthreads();
    }
    int n = b * 256 + t;
    int off = bs + (s[t] - v) + n;            // bucket base + in-bucket prefix + self slots
    if (n < NN) offsets[n] = off;
    cur[t] = off + 1;                          // real edges start after self-loop slot
    if (b == 0 && t == 0) offsets[NN] = NE + NN;
    __syncthreads();
    for (int i = bs + t; i < be; i += 256){
        u32 p = binsP[i];
        int dl = p >> 24;
        int pos = atomicAdd(&cur[dl], 1);
        src32[pos] = (int)(p & 0xFFFFFFu);
        ale1p[pos] = binsA[i];
        ale2p[pos] = binsA2[i];
    }
}

// ================= small precomputes =================
__global__ void k_q(const float* __restrict__ W1e, const float* __restrict__ a1e,
                    const float* __restrict__ W2e, const float* __restrict__ a2e,
                    float* __restrict__ q1, float* __restrict__ q2){
    int t = threadIdx.x;           // 64 threads
    int k = t >> 2, h = t & 3;
    float s = 0.f;
    for (int c = 0; c < 32; c++) s += W1e[k * 128 + h * 32 + c] * a1e[h * 32 + c];
    q1[t] = s;
    if (t < 16){
        float s2 = 0.f;
        for (int c = 0; c < 32; c++) s2 += W2e[t * 32 + c] * a2e[c];
        q2[t] = s2;
    }
}

__global__ __launch_bounds__(256) void k_ale(const float* __restrict__ eattr,
                                             const float* __restrict__ q1, const float* __restrict__ q2,
                                             u16* __restrict__ ale1, u16* __restrict__ ale2){
    __shared__ float sq1[64], sq2[16];
    int t = threadIdx.x;
    if (t < 64) sq1[t] = q1[t];
    if (t < 16) sq2[t] = q2[t];
    __syncthreads();
    int gt = blockIdx.x * 256 + t;                   // NE*4 exact
    int e = gt >> 2, part = gt & 3;
    f32x4 av = ((const f32x4*)eattr)[(size_t)e * 4 + part];
    int j0 = part * 4;
    float p0 = 0, p1 = 0, p2 = 0, p3 = 0, p4 = 0;
    #pragma unroll
    for (int k = 0; k < 4; k++){
        float a = av[k]; int j = j0 + k;
        p0 += a * sq1[j * 4 + 0]; p1 += a * sq1[j * 4 + 1];
        p2 += a * sq1[j * 4 + 2]; p3 += a * sq1[j * 4 + 3];
        p4 += a * sq2[j];
    }
    #pragma unroll
    for (int m = 1; m < 4; m <<= 1){
        p0 += __shfl_xor(p0, m); p1 += __shfl_xor(p1, m);
        p2 += __shfl_xor(p2, m); p3 += __shfl_xor(p3, m); p4 += __shfl_xor(p4, m);
    }
    if (part == 0){
        ushort4 w; w.x = f2bf(p0); w.y = f2bf(p1); w.z = f2bf(p2); w.w = f2bf(p3);
        ((ushort4*)ale1)[e] = w;
        ale2[e] = f2bf(p4);
    }
}

// ================= GEMMs (with fused al_s/al_d epilogues) =================
__global__ __launch_bounds__(256) void k_gemm1(const float* __restrict__ x, const float* __restrict__ W,
                                               const float* __restrict__ a1s, const float* __restrict__ a1d,
                                               u16* __restrict__ h1,
                                               float* __restrict__ al_s, float* __restrict__ al_d){
    __shared__ __align__(16) u16 sW[128 * 136];      // transposed: sW[col*136+k]
    int t = threadIdx.x;
    for (int i = t; i < 128 * 128; i += 256){
        int k = i >> 7, c = i & 127;
        sW[c * 136 + k] = f2bf(W[i]);
    }
    __syncthreads();
    int lane = t & 63, wave = t >> 6;
    int quad = lane >> 4, m16 = lane & 15;
    int rowA = blockIdx.x * 64 + wave * 16 + m16;
    bf16x8 afr[4];
    if (rowA < NN){
        const f32x4* xr = (const f32x4*)(x + (size_t)rowA * 128);
        #pragma unroll
        for (int kk = 0; kk < 4; kk++){
            f32x4 va = xr[kk * 8 + quad * 2];
            f32x4 vb = xr[kk * 8 + quad * 2 + 1];
            #pragma unroll
            for (int i2 = 0; i2 < 4; i2++){ afr[kk][i2] = (__bf16)va[i2]; afr[kk][4 + i2] = (__bf16)vb[i2]; }
        }
    } else {
        #pragma unroll
        for (int kk = 0; kk < 4; kk++)
            #pragma unroll
            for (int i2 = 0; i2 < 8; i2++) afr[kk][i2] = (__bf16)0.f;
    }
    int rowbase = blockIdx.x * 64 + wave * 16 + quad * 4;
    float vsA[4][4], vdA[4][4];
    #pragma unroll
    for (int r = 0; r < 4; r++)
        #pragma unroll
        for (int h = 0; h < 4; h++){ vsA[r][h] = 0.f; vdA[r][h] = 0.f; }
    #pragma unroll
    for (int nt = 0; nt < 8; nt++){
        f32x4 acc = (f32x4){0.f, 0.f, 0.f, 0.f};
        const u16* wp = &sW[(nt * 16 + m16) * 136 + quad * 8];
        #pragma unroll
        for (int kk = 0; kk < 4; kk++){
            bf16x8 bfr = *(const bf16x8*)(wp + kk * 32);
            acc = __builtin_amdgcn_mfma_f32_16x16x32_bf16(afr[kk], bfr, acc, 0, 0, 0);
        }
        int col = nt * 16 + m16;
        float cs = a1s[col], cd = a1d[col];
        const int h = nt >> 1;                       // head uniform per nt (16-col half of a 32-col head)
        #pragma unroll
        for (int r = 0; r < 4; r++){
            vsA[r][h] += acc[r] * cs;
            vdA[r][h] += acc[r] * cd;
            int row = rowbase + r;
            if (row < NN) h1[(size_t)row * 128 + col] = f2bf(acc[r]);
        }
    }
    // quad-local reduce (each quad owns all 128 cols of its 4 rows)
    #pragma unroll
    for (int r = 0; r < 4; r++)
        #pragma unroll
        for (int h = 0; h < 4; h++)
            #pragma unroll
            for (int m = 1; m < 16; m <<= 1){
                vsA[r][h] += __shfl_xor(vsA[r][h], m);
                vdA[r][h] += __shfl_xor(vdA[r][h], m);
            }
    int rs = m16 >> 2, hs = m16 & 3;                 // lane m16 writes (row rs, head hs)
    float s0 = sel4f(vsA[0][0], vsA[0][1], vsA[0][2], vsA[0][3], hs);
    float s1 = sel4f(vsA[1][0], vsA[1][1], vsA[1][2], vsA[1][3], hs);
    float s2 = sel4f(vsA[2][0], vsA[2][1], vsA[2][2], vsA[2][3], hs);
    float s3 = sel4f(vsA[3][0], vsA[3][1], vsA[3][2], vsA[3][3], hs);
    float d0 = sel4f(vdA[0][0], vdA[0][1], vdA[0][2], vdA[0][3], hs);
    float d1 = sel4f(vdA[1][0], vdA[1][1], vdA[1][2], vdA[1][3], hs);
    float d2 = sel4f(vdA[2][0], vdA[2][1], vdA[2][2], vdA[2][3], hs);
    float d3 = sel4f(vdA[3][0], vdA[3][1], vdA[3][2], vdA[3][3], hs);
    float souts = sel4f(s0, s1, s2, s3, rs);
    float soutd = sel4f(d0, d1, d2, d3, rs);
    int row = rowbase + rs;
    if (row < NN){
        al_s[row * 4 + hs] = souts;                  // 16 lanes -> 64B contiguous
        al_d[row * 4 + hs] = soutd;
    }
}

__global__ __launch_bounds__(256) void k_gemm2(const u16* __restrict__ hin, const float* __restrict__ W,
                                               const float* __restrict__ a2s, const float* __restrict__ a2d,
                                               float* __restrict__ h2a,
                                               float* __restrict__ al_s, float* __restrict__ al_d){
    __shared__ __align__(16) u16 sW[32 * 136];
    int t = threadIdx.x;
    for (int i = t; i < 128 * 32; i += 256){
        int k = i >> 5, c = i & 31;
        sW[c * 136 + k] = f2bf(W[i]);
    }
    __syncthreads();
    int lane = t & 63, wave = t >> 6;
    int quad = lane >> 4, m16 = lane & 15;
    int rowA = blockIdx.x * 64 + wave * 16 + m16;
    bf16x8 afr[4];
    if (rowA < NN){
        const u16* xr = hin + (size_t)rowA * 128 + quad * 8;
        #pragma unroll
        for (int kk = 0; kk < 4; kk++) afr[kk] = *(const bf16x8*)(xr + kk * 32);
    } else {
        #pragma unroll
        for (int kk = 0; kk < 4; kk++)
            #pragma unroll
            for (int i2 = 0; i2 < 8; i2++) afr[kk][i2] = (__bf16)0.f;
    }
    int rowbase = blockIdx.x * 64 + wave * 16 + quad * 4;
    float vs2[4], vd2[4];
    #pragma unroll
    for (int r = 0; r < 4; r++){ vs2[r] = 0.f; vd2[r] = 0.f; }
    #pragma unroll
    for (int nt = 0; nt < 2; nt++){
        f32x4 acc = (f32x4){0.f, 0.f, 0.f, 0.f};
        const u16* wp = &sW[(nt * 16 + m16) * 136 + quad * 8];
        #pragma unroll
        for (int kk = 0; kk < 4; kk++){
            bf16x8 bfr = *(const bf16x8*)(wp + kk * 32);
            acc = __builtin_amdgcn_mfma_f32_16x16x32_bf16(afr[kk], bfr, acc, 0, 0, 0);
        }
        int col = nt * 16 + m16;
        float cs = a2s[col], cd = a2d[col];
        #pragma unroll
        for (int r = 0; r < 4; r++){
            vs2[r] += acc[r] * cs;
            vd2[r] += acc[r] * cd;
            int row = rowbase + r;
            if (row < NN) h2a[(size_t)row * 32 + col] = acc[r];
        }
    }
    #pragma unroll
    for (int r = 0; r < 4; r++)
        #pragma unroll
        for (int m = 1; m < 16; m <<= 1){
            vs2[r] += __shfl_xor(vs2[r], m);
            vd2[r] += __shfl_xor(vd2[r], m);
        }
    if (m16 < 4){
        int row = rowbase + m16;
        if (row < NN){
            al_s[row] = sel4f(vs2[0], vs2[1], vs2[2], vs2[3], m16);
            al_d[row] = sel4f(vd2[0], vd2[1], vd2[2], vd2[3], m16);
        }
    }
}

// ================= layer 1: FUSED softmax + aggregate (single edge pass) =================
// 4 quarter-waves each own 1 edge; unnormalized p accumulated, 1/z applied at the end.
__global__ __launch_bounds__(256) void k_node1(const int* __restrict__ src32, const u16* __restrict__ ale1u,
                                               const int* __restrict__ offsets,
                                               const float* __restrict__ al_s, const float* __restrict__ al_d,
                                               const u16* __restrict__ h1, const float* __restrict__ b1,
                                               u16* __restrict__ h1b){
    int wave = threadIdx.x >> 6, lane = threadIdx.x & 63;
    int n = blockIdx.x * 4 + wave;               // 25000*4 = NN exact
    int start = offsets[n], end = offsets[n + 1];
    int degr = end - start - 1;
    int g = lane >> 4, l = lane & 15, hq = l >> 2;   // channels 8l..8l+7, head = l>>2
    float aldh = al_d[n * 4 + hq];
    const u32x4* h1v = (const u32x4*)h1;             // 16 u32x4 per row
    float acc[8];
    #pragma unroll
    for (int k = 0; k < 8; k++) acc[k] = 0.f;
    float z = 0.f, sa = 0.f;
    int i = start + 1 + g;
    int src = (i < end) ? __builtin_nontemporal_load(src32 + i) : 0;
    for (; i < end; i += 4){
        int ni = i + 4;
        int nsrc = (ni < end) ? __builtin_nontemporal_load(src32 + ni) : 0;
        float a = bf2f(__builtin_nontemporal_load(ale1u + (size_t)i * 4 + hq));
        float als = al_s[src * 4 + hq];
        u32x4 v = h1v[(size_t)src * 16 + l];
        float e = __expf(lreluf(als + aldh + a));
        z += e; sa += a;
        #pragma unroll
        for (int k = 0; k < 4; k++){
            acc[2 * k]     += e * bf2f((u16)(v[k] & 0xFFFFu));
            acc[2 * k + 1] += e * bf2f((u16)(v[k] >> 16));
        }
        src = nsrc;
    }
    // reduce z/sa across 4 groups (same head per l pattern under xor 16/32)
    z += __shfl_xor(z, 16); z += __shfl_xor(z, 32);
    sa += __shfl_xor(sa, 16); sa += __shfl_xor(sa, 32);
    float inv_deg = 1.f / fmaxf((float)degr, 1.f);
    float ps = __expf(lreluf(al_s[n * 4 + hq] + aldh + sa * inv_deg));
    z += ps;
    if (g == 0){                                     // self contribution, added once
        u32x4 v = h1v[(size_t)n * 16 + l];
        #pragma unroll
        for (int k = 0; k < 4; k++){
            acc[2 * k]     += ps * bf2f((u16)(v[k] & 0xFFFFu));
            acc[2 * k + 1] += ps * bf2f((u16)(v[k] >> 16));
        }
    }
    #pragma unroll
    for (int k = 0; k < 8; k++){
        acc[k] += __shfl_xor(acc[k], 16);
        acc[k] += __shfl_xor(acc[k], 32);
    }
    if (g == 0){
        float rz = 1.f / z;
        u32x4 w;
        #pragma unroll
        for (int k = 0; k < 4; k++){
            float v0 = eluf(acc[2 * k]     * rz + b1[l * 8 + 2 * k]);
            float v1 = eluf(acc[2 * k + 1] * rz + b1[l * 8 + 2 * k + 1]);
            w[k] = (u32)f2bf(v0) | ((u32)f2bf(v1) << 16);
        }
        ((u32x4*)h1b)[(size_t)n * 16 + l] = w;
    }
}

// ================= layer 2: FUSED softmax + aggregate =================
__global__ __launch_bounds__(256) void k_node2(const int* __restrict__ src32, const u16* __restrict__ ale2p,
                                               const int* __restrict__ offsets,
                                               const float* __restrict__ al_s, const float* __restrict__ al_d,
                                               const float* __restrict__ h2a, const float* __restrict__ b2,
                                               float* __restrict__ dout, float* __restrict__ rzv){
    int wave = threadIdx.x >> 6, lane = threadIdx.x & 63;
    int n = blockIdx.x * 4 + wave;
    int start = offsets[n], end = offsets[n + 1];
    int degr = end - start - 1;
    float aldn = al_d[n];
    int g = lane >> 3, l = lane & 7;                 // 8 edges in flight, channels l*4..l*4+3
    const f32x4* h2v = (const f32x4*)h2a;            // 8 f32x4 per row
    f32x4 acc = (f32x4){0.f, 0.f, 0.f, 0.f};
    float z = 0.f, sa = 0.f;
    int i = start + 1 + g;
    int src = (i < end) ? __builtin_nontemporal_load(src32 + i) : 0;
    for (; i < end; i += 8){
        int ni = i + 8;
        int nsrc = (ni < end) ? __builtin_nontemporal_load(src32 + ni) : 0;
        float a = bf2f(__builtin_nontemporal_load(ale2p + i));
        float als = al_s[src];
        f32x4 v = h2v[(size_t)src * 8 + l];
        float e = __expf(lreluf(als + aldn + a));
        z += e; sa += a;
        #pragma unroll
        for (int k = 0; k < 4; k++) acc[k] += e * v[k];
        src = nsrc;
    }
    z += __shfl_xor(z, 8); z += __shfl_xor(z, 16); z += __shfl_xor(z, 32);
    sa += __shfl_xor(sa, 8); sa += __shfl_xor(sa, 16); sa += __shfl_xor(sa, 32);
    float mal = sa / fmaxf((float)degr, 1.f);
    float ps = __expf(lreluf(al_s[n] + aldn + mal));
    z += ps;
    float rz = 1.f / z;
    if (g == 0){                                     // self contribution
        f32x4 v = h2v[(size_t)n * 8 + l];
        #pragma unroll
        for (int k = 0; k < 4; k++) acc[k] += ps * v[k];
    }
    if (lane == 0){
        rzv[n] = rz;
        dout[OUT_AL + NE + n] = ps * rz;             // self-loop alpha
        dout[OUT_EI + NE + n] = (float)n;            // self-loop edge_index entries
        dout[OUT_EI + NE2 + NE + n] = (float)n;
    }
    #pragma unroll
    for (int k = 0; k < 4; k++){
        acc[k] += __shfl_xor(acc[k], 8);
        acc[k] += __shfl_xor(acc[k], 16);
        acc[k] += __shfl_xor(acc[k], 32);
    }
    if (g == 0){
        f32x4 w;
        #pragma unroll
        for (int k = 0; k < 4; k++) w[k] = eluf(acc[k] + b2[l * 4 + k]);
        ((f32x4*)dout)[(size_t)n * 8 + l] = w;
    }
}

// alpha + edge_index for real edges, original edge order: all writes sequential
__global__ __launch_bounds__(256) void k_alpha(const int* __restrict__ ei, const u16* __restrict__ ale2,
                                               const float* __restrict__ al_s, const float* __restrict__ al_d,
                                               const float* __restrict__ rzv, float* __restrict__ dout){
    int e = blockIdx.x * 256 + threadIdx.x;          // NE exact
    int src = ei[e], dst = ei[NE + e];
    float a = bf2f(ale2[e]);
    float ev = __expf(lreluf(al_s[src] + al_d[dst] + a));
    __builtin_nontemporal_store(ev * rzv[dst], &dout[OUT_AL + e]);
    __builtin_nontemporal_store((float)src, &dout[OUT_EI + e]);
    __builtin_nontemporal_store((float)dst, &dout[OUT_EI + NE2 + e]);
}

extern "C" void kernel_launch(void* const* d_in, const int* in_sizes, int n_in,
                              void* d_out, int out_size, void* d_ws, size_t ws_size,
                              hipStream_t stream) {
    const float* x     = (const float*)d_in[0];
    const int*   ei    = (const int*)d_in[1];
    const float* eattr = (const float*)d_in[2];
    const float* W1    = (const float*)d_in[3];
    const float* W1e   = (const float*)d_in[4];
    const float* a1s   = (const float*)d_in[5];
    const float* a1d   = (const float*)d_in[6];
    const float* a1e   = (const float*)d_in[7];
    const float* b1    = (const float*)d_in[8];
    const float* W2    = (const float*)d_in[9];
    const float* W2e   = (const float*)d_in[10];
    const float* a2s   = (const float*)d_in[11];
    const float* a2d   = (const float*)d_in[12];
    const float* a2e   = (const float*)d_in[13];
    const float* b2    = (const float*)d_in[14];
    float* dout = (float*)d_out;

    char* ws = (char*)d_ws;
    size_t off = 0;
    auto alloc = [&](size_t bytes) -> void* {
        void* p = ws + off;
        off += (bytes + 255) & ~(size_t)255;
        return p;
    };
    // --- zero-initialized: bucket counters only ---
    int* bcnt = (int*)alloc((size_t)NB * 4);
    size_t zero_bytes = off;
    // --- rest fully written before read ---
    int*     offsets = (int*)alloc((size_t)(NN + 1) * 4);
    int*     bbase   = (int*)alloc((size_t)(NB + 1) * 4);
    int*     bcur    = (int*)alloc((size_t)NB * 4);
    u32*     binsP   = (u32*)alloc((size_t)NE * 4);          // dead after k_fscatter
    uint2*   binsA   = (uint2*)alloc((size_t)NE * 8);
    u16*     binsA2  = (u16*)alloc((size_t)NE * 2);
    int*     src32   = (int*)alloc((size_t)NE2 * 4);
    uint2*   ale1p   = (uint2*)alloc((size_t)NE2 * 8);
    u16*     ale2p   = (u16*)alloc((size_t)NE2 * 2);
    float*   q1      = (float*)alloc(64 * 4);
    float*   q2      = (float*)alloc(16 * 4);
    u16*     ale1    = (u16*)alloc((size_t)NE * 4 * 2);      // dead after k_bscatter
    u16*     ale2    = (u16*)alloc((size_t)NE * 2);          // live until k_alpha
    float*   al_s1   = (float*)alloc((size_t)NN * 4 * 4);
    float*   al_d1   = (float*)alloc((size_t)NN * 4 * 4);
    u16*     h1      = (u16*)alloc((size_t)NN * 128 * 2);    // dead after k_node1
    u16*     h1b     = (u16*)alloc((size_t)NN * 128 * 2);
    // aliases into dead h1 region (25.6 MB)
    char*  h1r   = (char*)h1;
    float* h2a   = (float*)(h1r);                            // NN*32*4 = 12.8 MB
    float* al_s2 = (float*)(h1r + 12800000);                 // NN*4
    float* al_d2 = (float*)(h1r + 13200128);                 // NN*4
    float* rzv   = (float*)(h1r + 13600256);                 // NN*4

    const int TB = 256;
    hipMemsetAsync(d_ws, 0, zero_bytes, stream);

    // precomputes
    k_q<<<1, 64, 0, stream>>>(W1e, a1e, W2e, a2e, q1, q2);
    k_ale<<<NE * 4 / TB, TB, 0, stream>>>(eattr, q1, q2, ale1, ale2);
    // bucketed CSR build
    k_bhist<<<NBB, TB, 0, stream>>>(ei, bcnt);
    k_bscan<<<1, 512, 0, stream>>>(bcnt, bbase, bcur);
    k_bscatter<<<NBB, TB, 0, stream>>>(ei, ale1, ale2, bcur, binsP, binsA, binsA2);
    k_fscatter<<<NB, TB, 0, stream>>>(binsP, binsA, binsA2, bbase, offsets, src32, ale1p, ale2p);
    // layer 1
    k_gemm1<<<(NN + 63) / 64, TB, 0, stream>>>(x, W1, a1s, a1d, h1, al_s1, al_d1);
    k_node1<<<NN / 4, TB, 0, stream>>>(src32, (const u16*)ale1p, offsets, al_s1, al_d1, h1, b1, h1b);
    // layer 2 (h1 region reused as h2a/al2/rzv)
    k_gemm2<<<(NN + 63) / 64, TB, 0, stream>>>(h1b, W2, a2s, a2d, h2a, al_s2, al_d2);
    k_node2<<<NN / 4, TB, 0, stream>>>(src32, ale2p, offsets, al_s2, al_d2, h2a, b2, dout, rzv);
    k_alpha<<<NE / TB, TB, 0, stream>>>(ei, ale2, al_s2, al_d2, rzv, dout);
}